// Round 7
// baseline (175.209 us; speedup 1.0000x reference)
//
#include <hip/hip_runtime.h>
#include <hip/hip_bf16.h>
#include <math.h>

#define T_TOK 4096
#define DIM   1024
#define HDIM  256
#define N_SH  2
#define N_RT  32
#define N_E   34
#define TOPK  4
#define TB    64
#define MAXPB 260
#define NSLOT 6
#define OSW   34          // ostage row stride (32 cols + 2 pad)

typedef short bf16x8 __attribute__((ext_vector_type(8)));
typedef float f32x4  __attribute__((ext_vector_type(4)));
typedef unsigned short u16x8 __attribute__((ext_vector_type(8)));

__device__ __forceinline__ ushort f2b(float v) {
    __hip_bfloat16 h = __float2bfloat16(v);
    return *reinterpret_cast<const ushort*>(&h);
}
__device__ __forceinline__ float b2f(ushort u) {
    unsigned int x = ((unsigned int)u) << 16;
    return __uint_as_float(x);
}
__device__ __forceinline__ float gelu_tanh(float x) {
    float z = 0.7978845608028654f * (x + 0.044715f * x * x * x);
    float e = __expf(2.0f * z);
    float t = 1.0f - 2.0f / (e + 1.0f);
    return 0.5f * x * (1.0f + t);
}

// ---- pack weights: src[E][K][N] fp32 -> per-MFMA-fragment bf16 tiles ----
template<int K, int N>
__global__ __launch_bounds__(256) void pack_weights(
    const float* __restrict__ srcS, const float* __restrict__ srcR,
    ushort* __restrict__ dst)
{
    const int e = blockIdx.y;
    const float* src = (e < N_SH) ? (srcS + (size_t)e * K * N)
                                  : (srcR + (size_t)(e - N_SH) * K * N);
    const int tid  = threadIdx.x;
    const int tile = blockIdx.x * 4 + (tid >> 6);
    const int lane = tid & 63;
    const int l16 = lane & 15, lk = lane >> 4;
    const int n16 = tile / (K / 32), k32 = tile % (K / 32);
    const int n  = n16 * 16 + l16;
    const int kb = k32 * 32 + lk * 8;
    const float* s = src + (size_t)kb * N + n;
    u16x8 o;
    #pragma unroll
    for (int j = 0; j < 8; ++j) o[j] = f2b(s[(size_t)j * N]);
    *(u16x8*)(dst + (size_t)e * K * N + (size_t)tile * 512 + lane * 8) = o;
}

// ---------------- RMSNorm + router softmax + top-4 (atomic-free) ----------------
__global__ __launch_bounds__(256) void rms_router_kernel(
    const float* __restrict__ x, const float* __restrict__ rms_w,
    const float* __restrict__ cent,
    ushort* __restrict__ xnb, float* __restrict__ y, float* __restrict__ aff_out,
    int* __restrict__ tk_e, float* __restrict__ sscore)
{
    const int t   = blockIdx.x;
    const int tid = threadIdx.x;
    const int wid = tid >> 6;
    const int lane = tid & 63;

    __shared__ float xsh[DIM];
    __shared__ float red[8];
    __shared__ float logits[N_RT];

    const float4 xv = ((const float4*)(x + (size_t)t * DIM))[tid];
    float ss = xv.x*xv.x + xv.y*xv.y + xv.z*xv.z + xv.w*xv.w;
    #pragma unroll
    for (int o = 32; o > 0; o >>= 1) ss += __shfl_down(ss, o);
    if (lane == 0) red[wid] = ss;
    __syncthreads();
    if (tid == 0) {
        float s = red[0] + red[1] + red[2] + red[3];
        red[4] = rsqrtf(s * (1.0f / (float)DIM) + 1e-6f);
    }
    __syncthreads();
    const float rstd = red[4];

    const float4 wv = ((const float4*)rms_w)[tid];
    float4 nv;
    nv.x = xv.x * rstd * wv.x;
    nv.y = xv.y * rstd * wv.y;
    nv.z = xv.z * rstd * wv.z;
    nv.w = xv.w * rstd * wv.w;

    ((float4*)(y + (size_t)t * DIM))[tid] = nv;     // residual init (fp32 xn)
    ushort4 xb = make_ushort4(f2b(nv.x), f2b(nv.y), f2b(nv.z), f2b(nv.w));
    ((ushort4*)(xnb + (size_t)t * DIM))[tid] = xb;
    ((float4*)xsh)[tid] = nv;
    __syncthreads();

    #pragma unroll
    for (int ei = 0; ei < 8; ++ei) {
        const int e = wid * 8 + ei;
        const float4* c4 = (const float4*)(cent + (size_t)e * DIM);
        float acc = 0.f;
        #pragma unroll
        for (int q = 0; q < 4; ++q) {
            float4 cv = c4[lane + 64*q];
            float4 xq = ((const float4*)xsh)[lane + 64*q];
            acc += cv.x*xq.x + cv.y*xq.y + cv.z*xq.z + cv.w*xq.w;
        }
        #pragma unroll
        for (int o = 32; o > 0; o >>= 1) acc += __shfl_down(acc, o);
        if (lane == 0) logits[e] = acc;
    }
    __syncthreads();

    if (wid == 0) {
        float v = (lane < N_RT) ? logits[lane] : -INFINITY;
        float m = v;
        #pragma unroll
        for (int o = 32; o > 0; o >>= 1) m = fmaxf(m, __shfl_xor(m, o));
        float p = (lane < N_RT) ? expf(v - m) : 0.f;
        float s = p;
        #pragma unroll
        for (int o = 32; o > 0; o >>= 1) s += __shfl_xor(s, o);
        const float a = p / s;
        if (lane < N_RT) aff_out[(size_t)t * N_RT + lane] = a;
        if (lane < N_SH) sscore[(size_t)t * NSLOT + lane] = 1.f;

        float vv = (lane < N_RT) ? a : -1.f;
        #pragma unroll
        for (int it = 0; it < TOPK; ++it) {
            float mx = vv;
            #pragma unroll
            for (int o = 32; o > 0; o >>= 1) mx = fmaxf(mx, __shfl_xor(mx, o));
            unsigned long long msk = __ballot(vv == mx);
            int sel = __ffsll((long long)msk) - 1;
            sel = (sel < 0) ? 0 : (sel & (N_RT - 1));
            if (lane == 0) {
                tk_e[(size_t)t * TOPK + it] = sel;
                sscore[(size_t)t * NSLOT + 2 + it] = mx;
            }
            if (lane == sel) vv = -1.f;
        }
    }
}

// ---- scatter: block e compacts (token,slot) entries where tk_e == e ----
__global__ __launch_bounds__(64) void scatter_kernel(
    const int* __restrict__ tk_e, int* __restrict__ counts, int* __restrict__ lists)
{
    const int e    = blockIdx.x;
    const int lane = threadIdx.x;
    const unsigned long long lt = (1ull << lane) - 1ull;   // lanes strictly below
    int base = 0;
    int* lst = lists + (size_t)e * T_TOK;
    for (int c = 0; c < T_TOK * TOPK; c += 256) {
        const int4 v = *(const int4*)(tk_e + c + lane * 4);
        const bool p0 = (v.x == e), p1 = (v.y == e), p2 = (v.z == e), p3 = (v.w == e);
        const unsigned long long m0 = __ballot(p0);
        const unsigned long long m1 = __ballot(p1);
        const unsigned long long m2 = __ballot(p2);
        const unsigned long long m3 = __ballot(p3);
        const int c0 = __popcll(m0), c1 = __popcll(m1), c2 = __popcll(m2);
        if (p0) lst[base + __popcll(m0 & lt)] = c + lane * 4 + 0;
        if (p1) lst[base + c0 + __popcll(m1 & lt)] = c + lane * 4 + 1;
        if (p2) lst[base + c0 + c1 + __popcll(m2 & lt)] = c + lane * 4 + 2;
        if (p3) lst[base + c0 + c1 + c2 + __popcll(m3 & lt)] = c + lane * 4 + 3;
        base += c0 + c1 + c2 + __popcll(m3);
    }
    if (lane == 0) counts[e] = base;
}

// ---- build XCD-bucketed work items: bucket b = e%8 gets expert e's tiles ----
__global__ void build_items(const int* __restrict__ counts,
                            int* __restrict__ bucket_cnt, int* __restrict__ items)
{
    const int e = threadIdx.x;           // 64 launched, 32 active
    int tiles = 0;
    if (e < N_RT) tiles = (counts[e] + TB - 1) / TB;
    const int grp = e >> 3;
    int pre = 0;
    #pragma unroll
    for (int g = 0; g < 4; ++g) {
        int tg = __shfl(tiles, (e & 7) + 8 * g, 64);
        if (g < grp) pre += tg;
    }
    if (e < N_RT) {
        for (int i = 0; i < tiles; ++i)
            items[(e & 7) * MAXPB + pre + i] = (e << 16) | i;
        if (grp == 3) bucket_cnt[e & 7] = pre + tiles;
    }
}

// ---------------- fused 2-layer expert MLP, bf16 MFMA, 64-token tiles ----------------
// 2-deep register prefetch pipeline in both phases.
template<bool ATOMIC>
__global__ __launch_bounds__(256, 3) void moe_mfma(
    const ushort* __restrict__ xnb,
    const ushort* __restrict__ W1p, const ushort* __restrict__ W2p,
    const float* __restrict__ sb1, const float* __restrict__ sb2,
    const float* __restrict__ rb1, const float* __restrict__ rb2,
    const int* __restrict__ counts, const int* __restrict__ lists,
    const int* __restrict__ bucket_cnt, const int* __restrict__ items,
    const float* __restrict__ sscore,
    ushort* __restrict__ sbuf, float* __restrict__ y)
{
    const int bi  = blockIdx.x;
    const int tid = threadIdx.x;

    __shared__ int    toks[TB];
    __shared__ int    orow[TB];
    __shared__ float  tscs[TB];
    __shared__ ushort hlds[TB * HDIM];          // 32 KB, XOR-swizzled
    __shared__ ushort ostage[4 * TB * OSW];     // 17 KB, per-wave repack

    int e_full;
    const float *b1, *b2;

    if (bi < 128) {                           // shared experts: 64 tiles x 2
        e_full = bi >> 6;
        const int tile = bi & 63;
        if (tid < TB) {
            const int t = tile * TB + tid;
            toks[tid] = t;
            orow[tid] = ATOMIC ? t : t * NSLOT + e_full;
            tscs[tid] = 1.f;
        }
        b1 = sb1 + e_full * HDIM;  b2 = sb2 + e_full * DIM;
    } else {                                  // routed: bucketed queue
        const int j = bi - 128;
        const int b = j & 7, pos = j >> 3;
        if (pos >= bucket_cnt[b]) return;
        const int v = items[b * MAXPB + pos];
        const int e = v >> 16, tile = v & 0xffff;
        e_full = N_SH + e;
        const int cnt = counts[e];
        if (tid < TB) {
            const int idx = tile * TB + tid;
            if (idx < cnt) {
                const int lv = lists[(size_t)e * T_TOK + idx];
                const int t = (lv >> 2) & (T_TOK - 1);     // hardened
                toks[tid] = t;
                orow[tid] = ATOMIC ? t : t * NSLOT + 2 + (lv & 3);
                tscs[tid] = ATOMIC ? sscore[(size_t)t * NSLOT + 2 + (lv & 3)] : 0.f;
            } else {
                toks[tid] = 0;
                orow[tid] = ATOMIC ? 0 : T_TOK * NSLOT;   // dummy row
                tscs[tid] = 0.f;
            }
        }
        b1 = rb1 + e * HDIM;  b2 = rb2 + e * DIM;
    }
    __syncthreads();

    const int w = tid >> 6, lane = tid & 63;
    const int l16 = lane & 15, lk = lane >> 4;

    const ushort* abase[4];
    #pragma unroll
    for (int mi = 0; mi < 4; ++mi)
        abase[mi] = xnb + (size_t)toks[mi * 16 + l16] * DIM + lk * 8;

    const ushort* W1e = W1p + (size_t)e_full * DIM * HDIM;
    const ushort* bbase[4];
    #pragma unroll
    for (int ni = 0; ni < 4; ++ni)
        bbase[ni] = W1e + (size_t)((w * 4 + ni) * 32) * 512 + lane * 8;

    f32x4 acc[4][4];
    #pragma unroll
    for (int mi = 0; mi < 4; ++mi)
        #pragma unroll
        for (int ni = 0; ni < 4; ++ni) acc[mi][ni] = (f32x4){0.f,0.f,0.f,0.f};

    // ---- phase 1: C1[64,256] = X @ W1, K=1024, 2-deep register pipeline ----
    bf16x8 apf[2][4], bpf[2][4];
    #pragma unroll
    for (int d = 0; d < 2; ++d) {
        #pragma unroll
        for (int ni = 0; ni < 4; ++ni)
            bpf[d][ni] = *(const bf16x8*)(bbase[ni] + (size_t)d * 512);
        #pragma unroll
        for (int mi = 0; mi < 4; ++mi)
            apf[d][mi] = *(const bf16x8*)(abase[mi] + d * 32);
    }

    #pragma unroll
    for (int k32 = 0; k32 < 32; ++k32) {
        const int cur = k32 & 1;
        #pragma unroll
        for (int ni = 0; ni < 4; ++ni)
            #pragma unroll
            for (int mi = 0; mi < 4; ++mi)
                acc[mi][ni] = __builtin_amdgcn_mfma_f32_16x16x32_bf16(apf[cur][mi], bpf[cur][ni], acc[mi][ni], 0, 0, 0);
        if (k32 + 2 < 32) {
            #pragma unroll
            for (int ni = 0; ni < 4; ++ni)
                bpf[cur][ni] = *(const bf16x8*)(bbase[ni] + (size_t)(k32 + 2) * 512);
            #pragma unroll
            for (int mi = 0; mi < 4; ++mi)
                apf[cur][mi] = *(const bf16x8*)(abase[mi] + (k32 + 2) * 32);
        }
    }

    // prefetch phase-2 steps s=0,1 (jc=0) before the h epilogue/barrier
    const ushort* W2e = W2p + (size_t)e_full * HDIM * DIM;
    bf16x8 bpf2[2][4];
    #pragma unroll
    for (int d = 0; d < 2; ++d)
        #pragma unroll
        for (int ni = 0; ni < 4; ++ni)
            bpf2[d][ni] = *(const bf16x8*)(W2e + (size_t)(((w * 4 + ni) * 8) + d) * 512 + lane * 8);

    // h = bf16(C1 + b1) -> swizzled LDS
    #pragma unroll
    for (int ni = 0; ni < 4; ++ni) {
        const int n = w * 64 + ni * 16 + l16;
        const float bv = b1[n];
        #pragma unroll
        for (int mi = 0; mi < 4; ++mi) {
            #pragma unroll
            for (int r = 0; r < 4; ++r) {
                const int m = mi * 16 + lk * 4 + r;
                const int byte = (m * (HDIM * 2) + n * 2) ^ ((m & 7) << 4);
                *(ushort*)((char*)hlds + byte) = f2b(acc[mi][ni][r] + bv);
            }
        }
    }
    __syncthreads();

    // ---- phase 2: C2[64,1024] = h @ W2, flattened 32-step pipeline over (jc,k) ----
    f32x4 acc2[4][4];
    #pragma unroll
    for (int mi = 0; mi < 4; ++mi)
        #pragma unroll
        for (int ni = 0; ni < 4; ++ni) acc2[mi][ni] = (f32x4){0.f,0.f,0.f,0.f};

    #pragma unroll
    for (int s = 0; s < 32; ++s) {
        const int jc  = s >> 3;
        const int k32 = s & 7;
        const int cur = s & 1;

        bf16x8 a2[4];
        #pragma unroll
        for (int mi = 0; mi < 4; ++mi) {
            const int m = mi * 16 + l16;
            const int byte = (m * (HDIM * 2) + (k32 * 32 + lk * 8) * 2) ^ ((m & 7) << 4);
            a2[mi] = *(const bf16x8*)((const char*)hlds + byte);
        }
        #pragma unroll
        for (int ni = 0; ni < 4; ++ni)
            #pragma unroll
            for (int mi = 0; mi < 4; ++mi)
                acc2[mi][ni] = __builtin_amdgcn_mfma_f32_16x16x32_bf16(a2[mi], bpf2[cur][ni], acc2[mi][ni], 0, 0, 0);

        if (s + 2 < 32) {
            const int s2 = s + 2;
            #pragma unroll
            for (int ni = 0; ni < 4; ++ni)
                bpf2[cur][ni] = *(const bf16x8*)(W2e + (size_t)((((s2 >> 3) * 16 + w * 4 + ni) * 8) + (s2 & 7)) * 512 + lane * 8);
        }

        if (k32 == 7) {
            // epilogue for this jc chunk
            if (ATOMIC) {
                #pragma unroll
                for (int ni = 0; ni < 4; ++ni) {
                    const int n = jc * 256 + w * 64 + ni * 16 + l16;
                    const float bv = b2[n];
                    #pragma unroll
                    for (int mi = 0; mi < 4; ++mi)
                        #pragma unroll
                        for (int r = 0; r < 4; ++r) {
                            const int m = mi * 16 + lk * 4 + r;
                            const float val = gelu_tanh(acc2[mi][ni][r] + bv) * tscs[m];
                            atomicAdd(&y[(size_t)orow[m] * DIM + n], val);
                        }
                }
            } else {
                // per-wave LDS repack (2 ni at a time) -> coalesced 64B-per-row stores
                ushort* os = ostage + w * (TB * OSW);
                #pragma unroll
                for (int p = 0; p < 2; ++p) {
                    asm volatile("s_waitcnt lgkmcnt(0)" ::: "memory");
                    #pragma unroll
                    for (int q = 0; q < 2; ++q) {
                        const int ni = p * 2 + q;
                        const float bv = b2[jc * 256 + w * 64 + ni * 16 + l16];
                        #pragma unroll
                        for (int mi = 0; mi < 4; ++mi)
                            #pragma unroll
                            for (int r = 0; r < 4; ++r) {
                                const int m = mi * 16 + lk * 4 + r;
                                os[m * OSW + q * 16 + l16] = f2b(acc2[mi][ni][r] + bv);
                            }
                    }
                    asm volatile("s_waitcnt lgkmcnt(0)" ::: "memory");
                    #pragma unroll
                    for (int rr = 0; rr < 4; ++rr) {
                        const int m  = rr * 16 + (lane >> 2);
                        const int nl = (lane & 3) * 8;
                        u16x8 vv = *(const u16x8*)(os + m * OSW + nl);
                        *(u16x8*)(sbuf + (size_t)orow[m] * DIM + jc * 256 + w * 64 + p * 32 + nl) = vv;
                    }
                }
            }
            #pragma unroll
            for (int mi = 0; mi < 4; ++mi)
                #pragma unroll
                for (int ni = 0; ni < 4; ++ni) acc2[mi][ni] = (f32x4){0.f,0.f,0.f,0.f};
        }
    }
}

// ---------------- gather: y = xn + sum_s gelu(slot)*score ----------------
__global__ __launch_bounds__(256) void gather_kernel(
    const ushort* __restrict__ sbuf, const float* __restrict__ sscore,
    float* __restrict__ y)
{
    const int idx = blockIdx.x * 256 + threadIdx.x;   // over T*DIM/4
    const int t = idx >> 8;
    const int d = (idx & 255) * 4;
    float4 a = ((float4*)y)[idx];
    #pragma unroll
    for (int s = 0; s < NSLOT; ++s) {
        const float sc = sscore[(size_t)t * NSLOT + s];
        const ushort4 u = *(const ushort4*)(sbuf + ((size_t)t * NSLOT + s) * DIM + d);
        a.x += gelu_tanh(b2f(u.x)) * sc;
        a.y += gelu_tanh(b2f(u.y)) * sc;
        a.z += gelu_tanh(b2f(u.z)) * sc;
        a.w += gelu_tanh(b2f(u.w)) * sc;
    }
    ((float4*)y)[idx] = a;
}

extern "C" void kernel_launch(void* const* d_in, const int* in_sizes, int n_in,
                              void* d_out, int out_size, void* d_ws, size_t ws_size,
                              hipStream_t stream) {
    const float* x      = (const float*)d_in[0];
    const float* rms_w  = (const float*)d_in[1];
    const float* cent   = (const float*)d_in[2];
    const float* sW1    = (const float*)d_in[3];
    const float* sb1    = (const float*)d_in[4];
    const float* sW2    = (const float*)d_in[5];
    const float* sb2    = (const float*)d_in[6];
    const float* rW1    = (const float*)d_in[7];
    const float* rb1    = (const float*)d_in[8];
    const float* rW2    = (const float*)d_in[9];
    const float* rb2    = (const float*)d_in[10];

    float* y_out   = (float*)d_out;
    float* aff_out = (float*)d_out + (size_t)T_TOK * DIM;

    char* p = (char*)d_ws;
    size_t off = 0;
    auto take = [&](size_t b) {
        char* r = p + off;
        off += (b + 255) & ~(size_t)255;
        return r;
    };
    ushort* xnb    = (ushort*)take((size_t)T_TOK * DIM * 2);
    ushort* W1p    = (ushort*)take((size_t)N_E * DIM * HDIM * 2);
    ushort* W2p    = (ushort*)take((size_t)N_E * HDIM * DIM * 2);
    int*    counts = (int*)take(N_RT * sizeof(int));
    int*    lists  = (int*)take((size_t)N_RT * T_TOK * 4);
    float*  sscore = (float*)take((size_t)T_TOK * NSLOT * 4);
    int*    tk_e   = (int*)take((size_t)T_TOK * TOPK * 4);
    int*    bcnt   = (int*)take(8 * sizeof(int));
    int*    items  = (int*)take((size_t)8 * MAXPB * 4);
    ushort* sbuf   = (ushort*)take(((size_t)T_TOK * NSLOT + TB) * DIM * 2);
    const bool slot_ok = (off <= ws_size);

    pack_weights<DIM,  HDIM><<<dim3(128, N_E), dim3(256), 0, stream>>>(sW1, rW1, W1p);
    pack_weights<HDIM, DIM ><<<dim3(128, N_E), dim3(256), 0, stream>>>(sW2, rW2, W2p);

    rms_router_kernel<<<dim3(T_TOK), dim3(256), 0, stream>>>(
        x, rms_w, cent, xnb, y_out, aff_out, tk_e, sscore);

    scatter_kernel<<<dim3(N_RT), dim3(64), 0, stream>>>(tk_e, counts, lists);
    build_items<<<dim3(1), dim3(64), 0, stream>>>(counts, bcnt, items);

    const int grid = 128 + 8 * MAXPB;
    if (slot_ok) {
        moe_mfma<false><<<dim3(grid), dim3(256), 0, stream>>>(
            xnb, W1p, W2p, sb1, sb2, rb1, rb2, counts, lists, bcnt, items,
            sscore, sbuf, y_out);
        gather_kernel<<<dim3((T_TOK * DIM / 4) / 256), dim3(256), 0, stream>>>(
            sbuf, sscore, y_out);
    } else {
        moe_mfma<true><<<dim3(grid), dim3(256), 0, stream>>>(
            xnb, W1p, W2p, sb1, sb2, rb1, rb2, counts, lists, bcnt, items,
            sscore, sbuf, y_out);
    }
}

// Round 9
// 165.034 us; speedup vs baseline: 1.0617x; 1.0617x over previous
//
#include <hip/hip_runtime.h>
#include <hip/hip_bf16.h>
#include <math.h>

#define T_TOK 4096
#define DIM   1024
#define HDIM  256
#define N_SH  2
#define N_RT  32
#define N_E   34
#define TOPK  4
#define TB    64
#define MAXPB 260
#define NSLOT 6
#define OSW   34          // ostage row stride (32 cols + 2 pad)

typedef short bf16x8 __attribute__((ext_vector_type(8)));
typedef float f32x4  __attribute__((ext_vector_type(4)));
typedef unsigned short u16x8 __attribute__((ext_vector_type(8)));

__device__ __forceinline__ ushort f2b(float v) {
    __hip_bfloat16 h = __float2bfloat16(v);
    return *reinterpret_cast<const ushort*>(&h);
}
__device__ __forceinline__ float b2f(ushort u) {
    unsigned int x = ((unsigned int)u) << 16;
    return __uint_as_float(x);
}
__device__ __forceinline__ float gelu_tanh(float x) {
    float z = 0.7978845608028654f * (x + 0.044715f * x * x * x);
    float e = __expf(2.0f * z);
    float t = 1.0f - 2.0f / (e + 1.0f);
    return 0.5f * x * (1.0f + t);
}

// async global->LDS, 16B per lane; lds dst is wave-uniform base (+lane*16 by HW)
__device__ __forceinline__ void gload_lds16(const ushort* g, ushort* l) {
    __builtin_amdgcn_global_load_lds(
        (const __attribute__((address_space(1))) void*)g,
        (__attribute__((address_space(3))) void*)l,
        16, 0, 0);
}

#define SBAR() __builtin_amdgcn_sched_barrier(0)

// ---- pack weights: src[E][K][N] fp32 -> per-MFMA-fragment bf16 tiles ----
template<int K, int N>
__global__ __launch_bounds__(256) void pack_weights(
    const float* __restrict__ srcS, const float* __restrict__ srcR,
    ushort* __restrict__ dst)
{
    const int e = blockIdx.y;
    const float* src = (e < N_SH) ? (srcS + (size_t)e * K * N)
                                  : (srcR + (size_t)(e - N_SH) * K * N);
    const int tid  = threadIdx.x;
    const int tile = blockIdx.x * 4 + (tid >> 6);
    const int lane = tid & 63;
    const int l16 = lane & 15, lk = lane >> 4;
    const int n16 = tile / (K / 32), k32 = tile % (K / 32);
    const int n  = n16 * 16 + l16;
    const int kb = k32 * 32 + lk * 8;
    const float* s = src + (size_t)kb * N + n;
    u16x8 o;
    #pragma unroll
    for (int j = 0; j < 8; ++j) o[j] = f2b(s[(size_t)j * N]);
    *(u16x8*)(dst + (size_t)e * K * N + (size_t)tile * 512 + lane * 8) = o;
}

// ---------------- RMSNorm + router softmax + top-4 (atomic-free) ----------------
__global__ __launch_bounds__(256) void rms_router_kernel(
    const float* __restrict__ x, const float* __restrict__ rms_w,
    const float* __restrict__ cent,
    ushort* __restrict__ xnb, float* __restrict__ y, float* __restrict__ aff_out,
    int* __restrict__ tk_e, float* __restrict__ sscore)
{
    const int t   = blockIdx.x;
    const int tid = threadIdx.x;
    const int wid = tid >> 6;
    const int lane = tid & 63;

    __shared__ float xsh[DIM];
    __shared__ float red[8];
    __shared__ float logits[N_RT];

    const float4 xv = ((const float4*)(x + (size_t)t * DIM))[tid];
    float ss = xv.x*xv.x + xv.y*xv.y + xv.z*xv.z + xv.w*xv.w;
    #pragma unroll
    for (int o = 32; o > 0; o >>= 1) ss += __shfl_down(ss, o);
    if (lane == 0) red[wid] = ss;
    __syncthreads();
    if (tid == 0) {
        float s = red[0] + red[1] + red[2] + red[3];
        red[4] = rsqrtf(s * (1.0f / (float)DIM) + 1e-6f);
    }
    __syncthreads();
    const float rstd = red[4];

    const float4 wv = ((const float4*)rms_w)[tid];
    float4 nv;
    nv.x = xv.x * rstd * wv.x;
    nv.y = xv.y * rstd * wv.y;
    nv.z = xv.z * rstd * wv.z;
    nv.w = xv.w * rstd * wv.w;

    ((float4*)(y + (size_t)t * DIM))[tid] = nv;     // residual init (fp32 xn)
    ushort4 xb = make_ushort4(f2b(nv.x), f2b(nv.y), f2b(nv.z), f2b(nv.w));
    ((ushort4*)(xnb + (size_t)t * DIM))[tid] = xb;
    ((float4*)xsh)[tid] = nv;
    __syncthreads();

    #pragma unroll
    for (int ei = 0; ei < 8; ++ei) {
        const int e = wid * 8 + ei;
        const float4* c4 = (const float4*)(cent + (size_t)e * DIM);
        float acc = 0.f;
        #pragma unroll
        for (int q = 0; q < 4; ++q) {
            float4 cv = c4[lane + 64*q];
            float4 xq = ((const float4*)xsh)[lane + 64*q];
            acc += cv.x*xq.x + cv.y*xq.y + cv.z*xq.z + cv.w*xq.w;
        }
        #pragma unroll
        for (int o = 32; o > 0; o >>= 1) acc += __shfl_down(acc, o);
        if (lane == 0) logits[e] = acc;
    }
    __syncthreads();

    if (wid == 0) {
        float v = (lane < N_RT) ? logits[lane] : -INFINITY;
        float m = v;
        #pragma unroll
        for (int o = 32; o > 0; o >>= 1) m = fmaxf(m, __shfl_xor(m, o));
        float p = (lane < N_RT) ? expf(v - m) : 0.f;
        float s = p;
        #pragma unroll
        for (int o = 32; o > 0; o >>= 1) s += __shfl_xor(s, o);
        const float a = p / s;
        if (lane < N_RT) aff_out[(size_t)t * N_RT + lane] = a;
        if (lane < N_SH) sscore[(size_t)t * NSLOT + lane] = 1.f;

        float vv = (lane < N_RT) ? a : -1.f;
        #pragma unroll
        for (int it = 0; it < TOPK; ++it) {
            float mx = vv;
            #pragma unroll
            for (int o = 32; o > 0; o >>= 1) mx = fmaxf(mx, __shfl_xor(mx, o));
            unsigned long long msk = __ballot(vv == mx);
            int sel = __ffsll((long long)msk) - 1;
            sel = (sel < 0) ? 0 : (sel & (N_RT - 1));
            if (lane == 0) {
                tk_e[(size_t)t * TOPK + it] = sel;
                sscore[(size_t)t * NSLOT + 2 + it] = mx;
            }
            if (lane == sel) vv = -1.f;
        }
    }
}

// ---- scatter: block e compacts (token,slot) entries where tk_e == e ----
__global__ __launch_bounds__(64) void scatter_kernel(
    const int* __restrict__ tk_e, int* __restrict__ counts, int* __restrict__ lists)
{
    const int e    = blockIdx.x;
    const int lane = threadIdx.x;
    const unsigned long long lt = (1ull << lane) - 1ull;   // lanes strictly below
    int base = 0;
    int* lst = lists + (size_t)e * T_TOK;
    for (int c = 0; c < T_TOK * TOPK; c += 256) {
        const int4 v = *(const int4*)(tk_e + c + lane * 4);
        const bool p0 = (v.x == e), p1 = (v.y == e), p2 = (v.z == e), p3 = (v.w == e);
        const unsigned long long m0 = __ballot(p0);
        const unsigned long long m1 = __ballot(p1);
        const unsigned long long m2 = __ballot(p2);
        const unsigned long long m3 = __ballot(p3);
        const int c0 = __popcll(m0), c1 = __popcll(m1), c2 = __popcll(m2);
        if (p0) lst[base + __popcll(m0 & lt)] = c + lane * 4 + 0;
        if (p1) lst[base + c0 + __popcll(m1 & lt)] = c + lane * 4 + 1;
        if (p2) lst[base + c0 + c1 + __popcll(m2 & lt)] = c + lane * 4 + 2;
        if (p3) lst[base + c0 + c1 + c2 + __popcll(m3 & lt)] = c + lane * 4 + 3;
        base += c0 + c1 + c2 + __popcll(m3);
    }
    if (lane == 0) counts[e] = base;
}

// ---- build XCD-bucketed work items: bucket b = e%8 gets expert e's tiles ----
__global__ void build_items(const int* __restrict__ counts,
                            int* __restrict__ bucket_cnt, int* __restrict__ items)
{
    const int e = threadIdx.x;           // 64 launched, 32 active
    int tiles = 0;
    if (e < N_RT) tiles = (counts[e] + TB - 1) / TB;
    const int grp = e >> 3;
    int pre = 0;
    #pragma unroll
    for (int g = 0; g < 4; ++g) {
        int tg = __shfl(tiles, (e & 7) + 8 * g, 64);
        if (g < grp) pre += tg;
    }
    if (e < N_RT) {
        for (int i = 0; i < tiles; ++i)
            items[(e & 7) * MAXPB + pre + i] = (e << 16) | i;
        if (grp == 3) bucket_cnt[e & 7] = pre + tiles;
    }
}

// ---------------- fused 2-layer expert MLP, bf16 MFMA, 64-token tiles ----------------
// Weights via global_load_lds, per-wave double buffer, counted vmcnt.
// Stage regions pinned with sched_barrier(0) + lgkmcnt(0) drain: guarantees
// (a) no ds_read of a buffer is outstanding when the DMA that overwrites it
//     is issued (reuse distance = 1), and
// (b) exactly the intended VMEM ops sit inside each counted-vmcnt window.
template<bool ATOMIC>
__global__ __launch_bounds__(256, 2) void moe_mfma(
    const ushort* __restrict__ xnb,
    const ushort* __restrict__ W1p, const ushort* __restrict__ W2p,
    const float* __restrict__ sb1, const float* __restrict__ sb2,
    const float* __restrict__ rb1, const float* __restrict__ rb2,
    const int* __restrict__ counts, const int* __restrict__ lists,
    const int* __restrict__ bucket_cnt, const int* __restrict__ items,
    const float* __restrict__ sscore,
    ushort* __restrict__ sbuf, float* __restrict__ y)
{
    const int bi  = blockIdx.x;
    const int tid = threadIdx.x;

    __shared__ int    toks[TB];
    __shared__ int    orow[TB];
    __shared__ float  tscs[TB];
    __shared__ ushort hlds[TB * HDIM];          // 32 KB, XOR-swizzled
    __shared__ ushort wstage[2 * 4 * 2048];     // 32 KB: [dbuf][wave][4 tiles x 512]
    __shared__ ushort ostage[4 * 32 * OSW];     // 8.7 KB, per-wave repack

    int e_full;
    const float *b1, *b2;

    if (bi < 128) {                           // shared experts: 64 tiles x 2
        e_full = bi >> 6;
        const int tile = bi & 63;
        if (tid < TB) {
            const int t = tile * TB + tid;
            toks[tid] = t;
            orow[tid] = ATOMIC ? t : t * NSLOT + e_full;
            tscs[tid] = 1.f;
        }
        b1 = sb1 + e_full * HDIM;  b2 = sb2 + e_full * DIM;
    } else {                                  // routed: bucketed queue
        const int j = bi - 128;
        const int b = j & 7, pos = j >> 3;
        if (pos >= bucket_cnt[b]) return;
        const int v = items[b * MAXPB + pos];
        const int e = v >> 16, tile = v & 0xffff;
        e_full = N_SH + e;
        const int cnt = counts[e];
        if (tid < TB) {
            const int idx = tile * TB + tid;
            if (idx < cnt) {
                const int lv = lists[(size_t)e * T_TOK + idx];
                const int t = (lv >> 2) & (T_TOK - 1);     // hardened
                toks[tid] = t;
                orow[tid] = ATOMIC ? t : t * NSLOT + 2 + (lv & 3);
                tscs[tid] = ATOMIC ? sscore[(size_t)t * NSLOT + 2 + (lv & 3)] : 0.f;
            } else {
                toks[tid] = 0;
                orow[tid] = ATOMIC ? 0 : T_TOK * NSLOT;   // dummy row
                tscs[tid] = 0.f;
            }
        }
        b1 = rb1 + e * HDIM;  b2 = rb2 + e * DIM;
    }
    __syncthreads();

    const int w = tid >> 6, lane = tid & 63;
    const int l16 = lane & 15, lk = lane >> 4;

    const ushort* abase[4];
    #pragma unroll
    for (int mi = 0; mi < 4; ++mi)
        abase[mi] = xnb + (size_t)toks[mi * 16 + l16] * DIM + lk * 8;

    const ushort* W1e = W1p + (size_t)e_full * DIM * HDIM;
    const ushort* W2e = W2p + (size_t)e_full * HDIM * DIM;
    ushort* ws_w = wstage + w * 2048;          // this wave's quarter (bufs at +0 / +8192)

    f32x4 acc[4][4];
    #pragma unroll
    for (int mi = 0; mi < 4; ++mi)
        #pragma unroll
        for (int ni = 0; ni < 4; ++ni) acc[mi][ni] = (f32x4){0.f,0.f,0.f,0.f};

    // ---- phase 1: C1[64,256] = X @ W1, K=1024 ----
    bf16x8 areg[2][4];
    SBAR();
    #pragma unroll
    for (int ni = 0; ni < 4; ++ni)
        gload_lds16(W1e + (size_t)((w * 4 + ni) * 32) * 512 + lane * 8, ws_w + ni * 512);
    #pragma unroll
    for (int mi = 0; mi < 4; ++mi)
        areg[0][mi] = *(const bf16x8*)(abase[mi]);
    SBAR();

    #pragma unroll
    for (int k = 0; k < 32; ++k) {
        const int cur = k & 1, nxt = cur ^ 1;
        if (k < 31) {
            SBAR();
            asm volatile("s_waitcnt lgkmcnt(0)" ::: "memory");   // prior ds_reads drained
            #pragma unroll
            for (int ni = 0; ni < 4; ++ni)
                gload_lds16(W1e + (size_t)((w * 4 + ni) * 32 + k + 1) * 512 + lane * 8,
                            ws_w + nxt * 8192 + ni * 512);
            #pragma unroll
            for (int mi = 0; mi < 4; ++mi)
                areg[nxt][mi] = *(const bf16x8*)(abase[mi] + (k + 1) * 32);
            SBAR();
            asm volatile("s_waitcnt vmcnt(8)" ::: "memory");     // step-k stage landed
            SBAR();
        } else {
            asm volatile("s_waitcnt vmcnt(0)" ::: "memory");
            SBAR();
        }
        bf16x8 bf[4];
        #pragma unroll
        for (int ni = 0; ni < 4; ++ni)
            bf[ni] = *(const bf16x8*)(ws_w + cur * 8192 + ni * 512 + lane * 8);
        #pragma unroll
        for (int ni = 0; ni < 4; ++ni)
            #pragma unroll
            for (int mi = 0; mi < 4; ++mi)
                acc[mi][ni] = __builtin_amdgcn_mfma_f32_16x16x32_bf16(areg[cur][mi], bf[ni], acc[mi][ni], 0, 0, 0);
    }

    // stage phase-2 step s=0 (jc=0,k32=0) into buf0 before the h barrier
    SBAR();
    asm volatile("s_waitcnt lgkmcnt(0)" ::: "memory");
    #pragma unroll
    for (int ni = 0; ni < 4; ++ni)
        gload_lds16(W2e + (size_t)((w * 4 + ni) * 8) * 512 + lane * 8, ws_w + ni * 512);
    SBAR();

    // h = bf16(C1 + b1) -> swizzled LDS
    #pragma unroll
    for (int ni = 0; ni < 4; ++ni) {
        const int n = w * 64 + ni * 16 + l16;
        const float bv = b1[n];
        #pragma unroll
        for (int mi = 0; mi < 4; ++mi) {
            #pragma unroll
            for (int r = 0; r < 4; ++r) {
                const int m = mi * 16 + lk * 4 + r;
                const int byte = (m * (HDIM * 2) + n * 2) ^ ((m & 7) << 4);
                *(ushort*)((char*)hlds + byte) = f2b(acc[mi][ni][r] + bv);
            }
        }
    }
    __syncthreads();   // drains vmcnt/lgkmcnt -> s=0 stage complete

    // ---- phase 2: C2[64,1024] = h @ W2, 32 steps over (jc,k32) ----
    f32x4 acc2[4][4];
    #pragma unroll
    for (int mi = 0; mi < 4; ++mi)
        #pragma unroll
        for (int ni = 0; ni < 4; ++ni) acc2[mi][ni] = (f32x4){0.f,0.f,0.f,0.f};

    #pragma unroll
    for (int s = 0; s < 32; ++s) {
        const int jc  = s >> 3;
        const int k32 = s & 7;
        const int cur = s & 1, nxt = cur ^ 1;

        if (s < 31) {
            SBAR();
            asm volatile("s_waitcnt lgkmcnt(0)" ::: "memory");   // prior ds_reads drained
            const int s2 = s + 1;
            #pragma unroll
            for (int ni = 0; ni < 4; ++ni)
                gload_lds16(W2e + (size_t)(((s2 >> 3) * 16 + w * 4 + ni) * 8 + (s2 & 7)) * 512 + lane * 8,
                            ws_w + nxt * 8192 + ni * 512);
            SBAR();
            asm volatile("s_waitcnt vmcnt(4)" ::: "memory");     // step-s stage landed
            SBAR();
        } else {
            asm volatile("s_waitcnt vmcnt(0)" ::: "memory");
            SBAR();
        }

        bf16x8 a2[4], bf2[4];
        #pragma unroll
        for (int mi = 0; mi < 4; ++mi) {
            const int m = mi * 16 + l16;
            const int byte = (m * (HDIM * 2) + (k32 * 32 + lk * 8) * 2) ^ ((m & 7) << 4);
            a2[mi] = *(const bf16x8*)((const char*)hlds + byte);
        }
        #pragma unroll
        for (int ni = 0; ni < 4; ++ni)
            bf2[ni] = *(const bf16x8*)(ws_w + cur * 8192 + ni * 512 + lane * 8);

        #pragma unroll
        for (int ni = 0; ni < 4; ++ni)
            #pragma unroll
            for (int mi = 0; mi < 4; ++mi)
                acc2[mi][ni] = __builtin_amdgcn_mfma_f32_16x16x32_bf16(a2[mi], bf2[ni], acc2[mi][ni], 0, 0, 0);

        if (k32 == 7) {
            if (ATOMIC) {
                #pragma unroll
                for (int ni = 0; ni < 4; ++ni) {
                    const int n = jc * 256 + w * 64 + ni * 16 + l16;
                    const float bv = b2[n];
                    #pragma unroll
                    for (int mi = 0; mi < 4; ++mi)
                        #pragma unroll
                        for (int r = 0; r < 4; ++r) {
                            const int m = mi * 16 + lk * 4 + r;
                            const float val = gelu_tanh(acc2[mi][ni][r] + bv) * tscs[m];
                            atomicAdd(&y[(size_t)orow[m] * DIM + n], val);
                        }
                }
            } else {
                // per-wave LDS repack in 4 quarter-rounds (2 ni x 2 mi-halves)
                ushort* os = ostage + w * (32 * OSW);
                #pragma unroll
                for (int mh = 0; mh < 2; ++mh) {
                    #pragma unroll
                    for (int p = 0; p < 2; ++p) {
                        asm volatile("s_waitcnt lgkmcnt(0)" ::: "memory");
                        #pragma unroll
                        for (int q = 0; q < 2; ++q) {
                            const int ni = p * 2 + q;
                            const float bv = b2[jc * 256 + w * 64 + ni * 16 + l16];
                            #pragma unroll
                            for (int mq = 0; mq < 2; ++mq) {
                                const int mi = mh * 2 + mq;
                                #pragma unroll
                                for (int r = 0; r < 4; ++r) {
                                    const int lm = mq * 16 + lk * 4 + r;
                                    os[lm * OSW + q * 16 + l16] = f2b(acc2[mi][ni][r] + bv);
                                }
                            }
                        }
                        asm volatile("s_waitcnt lgkmcnt(0)" ::: "memory");
                        #pragma unroll
                        for (int rr = 0; rr < 2; ++rr) {
                            const int lm = rr * 16 + (lane >> 2);
                            const int nl = (lane & 3) * 8;
                            u16x8 vv = *(const u16x8*)(os + lm * OSW + nl);
                            *(u16x8*)(sbuf + (size_t)orow[mh * 32 + lm] * DIM
                                      + jc * 256 + w * 64 + p * 32 + nl) = vv;
                        }
                    }
                }
            }
            #pragma unroll
            for (int mi = 0; mi < 4; ++mi)
                #pragma unroll
                for (int ni = 0; ni < 4; ++ni) acc2[mi][ni] = (f32x4){0.f,0.f,0.f,0.f};
        }
    }
}

// ---------------- gather: y = xn + sum_s gelu(slot)*score ----------------
__global__ __launch_bounds__(256) void gather_kernel(
    const ushort* __restrict__ sbuf, const float* __restrict__ sscore,
    float* __restrict__ y)
{
    const int idx = blockIdx.x * 256 + threadIdx.x;   // over T*DIM/4
    const int t = idx >> 8;
    const int d = (idx & 255) * 4;
    float4 a = ((float4*)y)[idx];
    #pragma unroll
    for (int s = 0; s < NSLOT; ++s) {
        const float sc = sscore[(size_t)t * NSLOT + s];
        const ushort4 u = *(const ushort4*)(sbuf + ((size_t)t * NSLOT + s) * DIM + d);
        a.x += gelu_tanh(b2f(u.x)) * sc;
        a.y += gelu_tanh(b2f(u.y)) * sc;
        a.z += gelu_tanh(b2f(u.z)) * sc;
        a.w += gelu_tanh(b2f(u.w)) * sc;
    }
    ((float4*)y)[idx] = a;
}

extern "C" void kernel_launch(void* const* d_in, const int* in_sizes, int n_in,
                              void* d_out, int out_size, void* d_ws, size_t ws_size,
                              hipStream_t stream) {
    const float* x      = (const float*)d_in[0];
    const float* rms_w  = (const float*)d_in[1];
    const float* cent   = (const float*)d_in[2];
    const float* sW1    = (const float*)d_in[3];
    const float* sb1    = (const float*)d_in[4];
    const float* sW2    = (const float*)d_in[5];
    const float* sb2    = (const float*)d_in[6];
    const float* rW1    = (const float*)d_in[7];
    const float* rb1    = (const float*)d_in[8];
    const float* rW2    = (const float*)d_in[9];
    const float* rb2    = (const float*)d_in[10];

    float* y_out   = (float*)d_out;
    float* aff_out = (float*)d_out + (size_t)T_TOK * DIM;

    char* p = (char*)d_ws;
    size_t off = 0;
    auto take = [&](size_t b) {
        char* r = p + off;
        off += (b + 255) & ~(size_t)255;
        return r;
    };
    ushort* xnb    = (ushort*)take((size_t)T_TOK * DIM * 2);
    ushort* W1p    = (ushort*)take((size_t)N_E * DIM * HDIM * 2);
    ushort* W2p    = (ushort*)take((size_t)N_E * HDIM * DIM * 2);
    int*    counts = (int*)take(N_RT * sizeof(int));
    int*    lists  = (int*)take((size_t)N_RT * T_TOK * 4);
    float*  sscore = (float*)take((size_t)T_TOK * NSLOT * 4);
    int*    tk_e   = (int*)take((size_t)T_TOK * TOPK * 4);
    int*    bcnt   = (int*)take(8 * sizeof(int));
    int*    items  = (int*)take((size_t)8 * MAXPB * 4);
    ushort* sbuf   = (ushort*)take(((size_t)T_TOK * NSLOT + TB) * DIM * 2);
    const bool slot_ok = (off <= ws_size);

    pack_weights<DIM,  HDIM><<<dim3(128, N_E), dim3(256), 0, stream>>>(sW1, rW1, W1p);
    pack_weights<HDIM, DIM ><<<dim3(128, N_E), dim3(256), 0, stream>>>(sW2, rW2, W2p);

    rms_router_kernel<<<dim3(T_TOK), dim3(256), 0, stream>>>(
        x, rms_w, cent, xnb, y_out, aff_out, tk_e, sscore);

    scatter_kernel<<<dim3(N_RT), dim3(64), 0, stream>>>(tk_e, counts, lists);
    build_items<<<dim3(1), dim3(64), 0, stream>>>(counts, bcnt, items);

    const int grid = 128 + 8 * MAXPB;
    if (slot_ok) {
        moe_mfma<false><<<dim3(grid), dim3(256), 0, stream>>>(
            xnb, W1p, W2p, sb1, sb2, rb1, rb2, counts, lists, bcnt, items,
            sscore, sbuf, y_out);
        gather_kernel<<<dim3((T_TOK * DIM / 4) / 256), dim3(256), 0, stream>>>(
            sbuf, sscore, y_out);
    } else {
        moe_mfma<true><<<dim3(grid), dim3(256), 0, stream>>>(
            xnb, W1p, W2p, sb1, sb2, rb1, rb2, counts, lists, bcnt, items,
            sscore, sbuf, y_out);
    }
}